// Round 3
// baseline (354.345 us; speedup 1.0000x reference)
//
#include <hip/hip_runtime.h>

// ---------------------------------------------------------------- constants
#define TTOK 32768
#define DM   256
#define NF   1024
#define KMAX 32

typedef __attribute__((ext_vector_type(8))) unsigned short ushort8;
typedef __attribute__((ext_vector_type(8))) __bf16 bf16x8;
typedef __attribute__((ext_vector_type(4))) float floatx4;
typedef __attribute__((ext_vector_type(2))) float floatx2;

// packed f32 math (lowers to v_pk_fma_f32 / v_pk_max_f32 / v_pk_min_f32)
#define PKFMA(a,b,c) __builtin_elementwise_fma(a,b,c)
#define PKMAX(a,b)   __builtin_elementwise_max(a,b)
#define PKMIN(a,b)   __builtin_elementwise_min(a,b)

// workspace offsets (all 256B aligned)
constexpr size_t O_SLOT = 0;                                   // 1 uint (max|Wt|)
constexpr size_t O_S    = 256;                                 // 1024 f32 sigmoid(alpha)
constexpr size_t O_WCT  = O_S    + 4096;                       // Wc^T  [1024][256] bf16
constexpr size_t O_WGT  = O_WCT  + (size_t)NF*DM*2;            // Wg^T  [1024][256] bf16
constexpr size_t O_WDT  = O_WGT  + (size_t)NF*DM*2;            // Wd^T  [256][1024] bf16
constexpr size_t O_WTT  = O_WDT  + (size_t)DM*NF*2;            // Wt^T  [256][1024] f32
constexpr size_t O_XBF  = O_WTT  + (size_t)DM*NF*4;            // x bf16 [T][256]
constexpr size_t O_CNT  = O_XBF  + (size_t)TTOK*DM*2;          // counts [T]
constexpr size_t O_CIDX = O_CNT  + (size_t)TTOK*4;             // cand d (raw) [T][KMAX]
constexpr size_t O_CVAL = O_CIDX + (size_t)TTOK*KMAX*4;        // cand val [T][KMAX]
constexpr size_t O_FUSD = O_CVAL + (size_t)TTOK*KMAX*4;        // fused bf16 [T][1024]

__device__ __forceinline__ float bf2f(unsigned short u) {
    union { unsigned int i; float f; } c; c.i = ((unsigned int)u) << 16; return c.f;
}
__device__ __forceinline__ unsigned short f2bf(float v) {
    union { float f; unsigned int i; } c; c.f = v;
    unsigned int b = c.i;
    return (unsigned short)((b + 0x7FFFu + ((b >> 16) & 1u)) >> 16);
}
__device__ __forceinline__ float sigm(float z) { return 1.0f / (1.0f + __expf(-z)); }
// tanh-gelu: max |diff| vs exact erf-gelu ~3e-3, far under tolerance
__device__ __forceinline__ float gelu_f(float x) {
    return x * sigm(1.59576912f * (x + 0.044715f * x * x * x));
}
// async global->LDS, 16B per lane; lds dest = wave-uniform base + lane*16 [m97/m104]
__device__ __forceinline__ void g2lds16(const unsigned short* g, unsigned short* l) {
    __builtin_amdgcn_global_load_lds((const __attribute__((address_space(1))) unsigned int*)g,
                                     (__attribute__((address_space(3))) unsigned int*)l, 16, 0, 0);
}

// ------------------------------------------------- kernel 1: pack weights (+ max|Wt| fused)
// r9: minmax_kernel folded in -- the WtT transpose already reads every Wt
// element once; wave-reduce |w| and atomicMax (device-scope, m20). slot is
// zeroed by hipMemsetAsync on the stream before this launch (init inside the
// kernel would race the atomics).
__global__ void pack_kernel(const float* __restrict__ Wt, const float* __restrict__ alpha,
                            const float* __restrict__ Wc, const float* __restrict__ Wg,
                            const float* __restrict__ Wd,
                            unsigned short* __restrict__ Wct, unsigned short* __restrict__ Wgt,
                            unsigned short* __restrict__ WdT, float* __restrict__ WtT,
                            float* __restrict__ s, unsigned int* __restrict__ slot) {
    int e = blockIdx.x * 256 + threadIdx.x;
    { int f = e >> 8, k = e & 255;           // Wc/Wg are [256][1024]
      Wct[e] = f2bf(Wc[k * NF + f]);
      Wgt[e] = f2bf(Wg[k * NF + f]); }
    { int n = e >> 10, k = e & 1023;         // Wd is [1024][256]
      WdT[e] = f2bf(Wd[k * DM + n]); }
    float wv;
    { int d = e >> 10, f = e & 1023;         // Wt is [1024][256]
      wv = Wt[f * DM + d];
      WtT[e] = wv; }
    float lm = fabsf(wv);
    #pragma unroll
    for (int o = 32; o > 0; o >>= 1) lm = fmaxf(lm, __shfl_xor(lm, o));
    if ((threadIdx.x & 63) == 0) atomicMax(slot, __float_as_uint(lm)); // |w|>=0: uint order ok
    if (e < NF) s[e] = sigm(alpha[e]);
}

// ------------------------------------------------- kernel 3: candidates + x->bf16
// wave-per-token; ballot+prefix-popcount compaction, no LDS, no atomics.
__global__ __launch_bounds__(256) void cand_kernel(
        const float* __restrict__ x, const unsigned int* __restrict__ slot,
        unsigned short* __restrict__ xbf, int* __restrict__ counts,
        int* __restrict__ cidx, float* __restrict__ cval) {
    const int wave = threadIdx.x >> 6, lane = threadIdx.x & 63;
    const int tok = blockIdx.x * 4 + wave;
    const float* xr = x + (size_t)tok * DM;
    float v0 = xr[lane], v1 = xr[lane + 64], v2 = xr[lane + 128], v3 = xr[lane + 192];
    unsigned short* xo = xbf + (size_t)tok * DM;
    xo[lane]       = f2bf(v0);
    xo[lane + 64]  = f2bf(v1);
    xo[lane + 128] = f2bf(v2);
    xo[lane + 192] = f2bf(v3);
    float m = fmaxf(fmaxf(v0, v1), fmaxf(v2, v3));
    #pragma unroll
    for (int o = 32; o > 0; o >>= 1) m = fmaxf(m, __shfl_xor(m, o));
    const float delta = 2.0f * __uint_as_float(*slot);  // >= Wmax-Wmin: exact exclusion bound
    const float thr = m - delta;
    const unsigned long long lt = (lane == 63) ? 0x7FFFFFFFFFFFFFFFull
                                               : ((1ull << lane) - 1ull);
    float vv[4] = { v0, v1, v2, v3 };
    int base = 0;
    #pragma unroll
    for (int j = 0; j < 4; j++) {
        bool p = vv[j] >= thr;
        unsigned long long mask = __ballot(p);
        int pos = base + __popcll(mask & lt);
        if (p && pos < KMAX) {
            cidx[(size_t)tok * KMAX + pos] = lane + j * 64;
            cval[(size_t)tok * KMAX + pos] = vv[j];
        }
        base += __popcll(mask);
    }
    if (lane == 0) counts[tok] = base;
}

// ------------------------------------------------- kernel 4: fused GEMM1
// (x@Wc, x@Wg) MFMA + tropical max-plus + convex/concave + gate blend.
// 128x128 tile, BK=32, 512 thr (8 waves 2Mx4F, wave 64x32 dual-output).
// Structure ledger:
//  r7 (REVERTED): 128x64 tile + (512,6) -> spills + L2 thrash. acc-64 waves
//    are structurally 4 w/SIMD; don't diet registers.
//  r8 lesson: prestaging par/sOV BEFORE the K-loop raised entry pressure ->
//    72 B/thread scratch (WRITE +72MB, FETCH +55MB readback). REVERTED: par/
//    sOV staged post-loop (r6 position, overlaps k=7 compute of other waves).
//  r8 kept: single-barrier double-buffered K-loop (2x24KB stage bufs).
//  r9 new: packed-f32 epilogue -- v_pk_fma/pk_max/pk_min pairs PWL segments
//    (8 inst/hull vs 15) and packs the z-gather across the (f0,f0+16) column
//    pair. ~-30% epilogue VALU; VALUBusy was 58-60% -> VALU-issue matters.
// NOT chased: SQ_LDS_BANK_CONFLICT ~4.8M -- af/bf ds_read_b128 covers dense
// contiguous 1KB (16 rows x 64B); density-optimal, swizzle can't help.
#define LDSS  32     // ushorts per LDS row, no pad (wave-uniform-base DMA, m104)
#define KCAP  16
#define KPADL 17
#define OSTR  136    // obuf row stride in ushorts (272B, 16q+4r+col bank spread)
#define STAGEB 24576 // bytes per stage buffer (As 8K | Bcs 8K | Bgs 8K)
__global__ __launch_bounds__(512, 4) void gemm1_kernel(
    const unsigned short* __restrict__ A,   // xbf [T][256]
    const unsigned short* __restrict__ Bct, // [1024][256]
    const unsigned short* __restrict__ Bgt, // [1024][256]
    const float* __restrict__ bc, const float* __restrict__ bg,
    const int* __restrict__ counts, const int* __restrict__ cidx,
    const float* __restrict__ cval, const float* __restrict__ x,
    const float* __restrict__ WtT, const float* __restrict__ bt,
    const float* __restrict__ slx, const float* __restrict__ ofx,
    const float* __restrict__ slc, const float* __restrict__ ofc,
    const float* __restrict__ s, unsigned short* __restrict__ fused) {
    __shared__ __align__(16) char smem[76800];
    // [0,24576) stage buf0 ; [24576,49152) stage buf1
    unsigned short* obuf = (unsigned short*)smem;       // post-loop overlay [0,34816)
    float* par = (float*)(smem + 49152);                // [49152,67584) 128 x 36 f32
    int* sOV  = (int*)(smem + 67584);                   // [67584,76288) 128 x KPADL
    int* sCnt = (int*)(smem + 76288);                   // [76288,76800)
    const int t = threadIdx.x;
    // XCD-aware swizzle: 8 bf-siblings of a bm consecutive within one XCD's
    // stream -> A-tile + meta L2-hot (r6 lesson; FETCH 29MB confirms)
    const int b = blockIdx.x;
    const int xcd = b & 7, j = b >> 3;
    const int bf = j & 7;
    const int bm = (j >> 3) * 8 + xcd;
    const int wave = t >> 6, lane = t & 63;
    const int wm = wave & 1, wn = wave >> 1;
    const int lr = lane & 15, quad = lane >> 4;
    const int srow = wave * 16 + (lane >> 2), scol = (lane & 3) << 3;
    const unsigned short* gA = A   + (size_t)(bm * 128 + srow) * DM + scol;
    const unsigned short* gC = Bct + (size_t)(bf * 128 + srow) * DM + scol;
    const unsigned short* gG = Bgt + (size_t)(bf * 128 + srow) * DM + scol;
    const int lofs = wave * 16 * LDSS;  // per-wave staging dest offset (ushorts)

    if (t < 128) sCnt[t] = counts[bm * 128 + t];   // cheap; published by 1st barrier

    floatx4 accc[4][2], accg[4][2];
    #pragma unroll
    for (int i = 0; i < 4; i++)
        #pragma unroll
        for (int jj = 0; jj < 2; jj++) { accc[i][jj] = (floatx4)0.0f; accg[i][jj] = (floatx4)0.0f; }

    // ---- K-loop: double-buffered, one barrier per step ----
    {
        unsigned short* b0 = (unsigned short*)smem;
        g2lds16(gA, b0 + lofs);
        g2lds16(gC, b0 + 4096 + lofs);
        g2lds16(gG, b0 + 8192 + lofs);
    }
    __syncthreads();   // publishes stage0 + sCnt
    #pragma unroll
    for (int k = 0; k < 8; k++) {
        unsigned short* cur = (unsigned short*)(smem + (size_t)(k & 1) * STAGEB);
        if (k < 7) {
            unsigned short* nxt = (unsigned short*)(smem + (size_t)((k + 1) & 1) * STAGEB);
            int k0 = (k + 1) * 32;
            g2lds16(gA + k0, nxt + lofs);
            g2lds16(gC + k0, nxt + 4096 + lofs);
            g2lds16(gG + k0, nxt + 8192 + lofs);
        }
        bf16x8 af[4], bcf[2], bgf[2];
        #pragma unroll
        for (int mi = 0; mi < 4; mi++)
            af[mi] = *(const bf16x8*)&cur[(wm * 64 + mi * 16 + lr) * LDSS + quad * 8];
        #pragma unroll
        for (int ni = 0; ni < 2; ni++) {
            bcf[ni] = *(const bf16x8*)&cur[4096 + (wn * 32 + ni * 16 + lr) * LDSS + quad * 8];
            bgf[ni] = *(const bf16x8*)&cur[8192 + (wn * 32 + ni * 16 + lr) * LDSS + quad * 8];
        }
        #pragma unroll
        for (int mi = 0; mi < 4; mi++)
            #pragma unroll
            for (int ni = 0; ni < 2; ni++) {
                accc[mi][ni] = __builtin_amdgcn_mfma_f32_16x16x32_bf16(af[mi], bcf[ni], accc[mi][ni], 0, 0, 0);
                accg[mi][ni] = __builtin_amdgcn_mfma_f32_16x16x32_bf16(af[mi], bgf[ni], accg[mi][ni], 0, 0, 0);
            }
        if (k < 7) __syncthreads();   // stage k+1 complete; cur reusable
    }

    // ---- post-loop staging (r6 position: low pressure; overlaps k=7 compute
    //      of other waves -- regions are disjoint from stage bufs) ----
    const int PADV = (int)(((unsigned int)f2bf(-1e30f)) << 16);
    for (int e = t; e < 2048; e += 512) {            // 128 rows x KCAP
        int m = e >> 4, k = e & 15;
        int c = sCnt[m];
        int pk = PADV;
        if (k < (c < KCAP ? c : KCAP)) {
            int d  = cidx[(size_t)(bm * 128 + m) * KMAX + k];
            float v = cval[(size_t)(bm * 128 + m) * KMAX + k];
            pk = (int)(((unsigned int)f2bf(v)) << 16) | d;
        }
        sOV[m * KPADL + k] = pk;
    }
    // par[fl*36 + {0..7 slx, 8..15 ofx, 16..23 slc, 24..31 ofc, 32 bt, 33 s, 34 bc, 35 bg}]
    for (int e = t; e < 1024; e += 512) {
        int ff = e >> 3, w = e & 7;
        int gf = (bf * 128 + ff) * 8 + w;
        par[ff * 36 + w]      = slx[gf];
        par[ff * 36 + 8 + w]  = ofx[gf];
        par[ff * 36 + 16 + w] = slc[gf];
        par[ff * 36 + 24 + w] = ofc[gf];
    }
    if (t < 128) {
        int gf = bf * 128 + t;
        par[t * 36 + 32] = bt[gf];
        par[t * 36 + 33] = s[gf];
        par[t * 36 + 34] = bc[gf];
        par[t * 36 + 35] = bg[gf];
    }
    __syncthreads();   // publishes par/sOV; all k=7 stage-buf reads done -> obuf overlay safe

    // ---- fused epilogue: tropical z + convex/concave + gate blend ----
    // C/D layout col=lane&15, row=quad*4+r  [verified m89/m91]
    const int f0 = bf * 128 + wn * 32 + lr;    // ni=0 global f; ni=1 is +16
    #pragma unroll
    for (int mi = 0; mi < 4; mi++) {
        const int mb = wm * 64 + mi * 16 + quad * 4;   // local m of r=0
        int c0 = sCnt[mb], c1 = sCnt[mb + 1], c2 = sCnt[mb + 2], c3 = sCnt[mb + 3];
        int k0c = c0 < KCAP ? c0 : KCAP, k1c = c1 < KCAP ? c1 : KCAP;
        int k2c = c2 < KCAP ? c2 : KCAP, k3c = c3 < KCAP ? c3 : KCAP;
        int km = max(max(k0c, k1c), max(k2c, k3c));
        // z packed across the (f0, f0+16) column pair: .x = ni0, .y = ni1
        floatx2 zp0 = { -1e30f, -1e30f }, zp1 = zp0, zp2 = zp0, zp3 = zp0;
        for (int k = 0; k < km; k++) {
            int p0 = sOV[(mb + 0) * KPADL + k];
            int p1 = sOV[(mb + 1) * KPADL + k];
            int p2 = sOV[(mb + 2) * KPADL + k];
            int p3 = sOV[(mb + 3) * KPADL + k];
            const float* r0 = WtT + ((p0 & 0xFFFF) << 10) + f0;
            const float* r1 = WtT + ((p1 & 0xFFFF) << 10) + f0;
            const float* r2 = WtT + ((p2 & 0xFFFF) << 10) + f0;
            const float* r3 = WtT + ((p3 & 0xFFFF) << 10) + f0;
            floatx2 w0 = { r0[0], r0[16] };
            floatx2 w1 = { r1[0], r1[16] };
            floatx2 w2 = { r2[0], r2[16] };
            floatx2 w3 = { r3[0], r3[16] };
            float s0 = __int_as_float(p0 & 0xFFFF0000);
            float s1 = __int_as_float(p1 & 0xFFFF0000);
            float s2 = __int_as_float(p2 & 0xFFFF0000);
            float s3 = __int_as_float(p3 & 0xFFFF0000);
            floatx2 v0 = { s0, s0 }, v1 = { s1, s1 }, v2 = { s2, s2 }, v3 = { s3, s3 };
            zp0 = PKMAX(zp0, v0 + w0);
            zp1 = PKMAX(zp1, v1 + w1);
            zp2 = PKMAX(zp2, v2 + w2);
            zp3 = PKMAX(zp3, v3 + w3);
        }
        // exact fallback (count > KCAP, ~never): full 256-d scan
        if (c0 > KCAP || c1 > KCAP || c2 > KCAP || c3 > KCAP) {
            float za[4] = { zp0.x, zp1.x, zp2.x, zp3.x };
            float zb[4] = { zp0.y, zp1.y, zp2.y, zp3.y };
            int cc[4] = { c0, c1, c2, c3 };
            #pragma unroll 1
            for (int r = 0; r < 4; r++) if (cc[r] > KCAP) {
                const float* xr = x + (size_t)(bm * 128 + mb + r) * DM;
                float ma = -1e30f, mbv = -1e30f;
                for (int d = 0; d < DM; d++) {
                    float xv = xr[d];
                    ma  = fmaxf(ma,  xv + WtT[d * NF + f0]);
                    mbv = fmaxf(mbv, xv + WtT[d * NF + f0 + 16]);
                }
                za[r] = ma; zb[r] = mbv;
            }
            zp0.x = za[0]; zp1.x = za[1]; zp2.x = za[2]; zp3.x = za[3];
            zp0.y = zb[0]; zp1.y = zb[1]; zp2.y = zb[2]; zp3.y = zb[3];
        }
        float z0a = zp0.x, z0b = zp0.y, z1a = zp1.x, z1b = zp1.y;
        float z2a = zp2.x, z2b = zp2.y, z3a = zp3.x, z3b = zp3.y;
        #pragma unroll
        for (int ni = 0; ni < 2; ni++) {
            const int fl = wn * 32 + ni * 16 + lr;
            const float* pp = par + fl * 36;
            float4 a0 = *(const float4*)(pp),      a1 = *(const float4*)(pp + 4);
            float4 b0 = *(const float4*)(pp + 8),  b1 = *(const float4*)(pp + 12);
            float4 cc0 = *(const float4*)(pp + 16), cc1 = *(const float4*)(pp + 20);
            float4 d0 = *(const float4*)(pp + 24), d1 = *(const float4*)(pp + 28);
            float4 sc = *(const float4*)(pp + 32);  // bt, s, bc, bg
            // segment-pair packing for the PWL hulls (v_pk_fma/pk_max/pk_min)
            floatx2 sA0 = { a0.x, a0.y }, sA1 = { a0.z, a0.w };
            floatx2 sA2 = { a1.x, a1.y }, sA3 = { a1.z, a1.w };
            floatx2 oA0 = { b0.x, b0.y }, oA1 = { b0.z, b0.w };
            floatx2 oA2 = { b1.x, b1.y }, oA3 = { b1.z, b1.w };
            floatx2 sC0 = { cc0.x, cc0.y }, sC1 = { cc0.z, cc0.w };
            floatx2 sC2 = { cc1.x, cc1.y }, sC3 = { cc1.z, cc1.w };
            floatx2 oC0 = { d0.x, d0.y }, oC1 = { d0.z, d0.w };
            floatx2 oC2 = { d1.x, d1.y }, oC3 = { d1.z, d1.w };
            float zr[4];
            if (ni == 0) { zr[0] = z0a; zr[1] = z1a; zr[2] = z2a; zr[3] = z3a; }
            else         { zr[0] = z0b; zr[1] = z1b; zr[2] = z2b; zr[3] = z3b; }
            #pragma unroll
            for (int r = 0; r < 4; r++) {
                float zv = zr[r] + sc.x;
                floatx2 zz = { zv, zv };
                floatx2 tx = PKMAX(PKMAX(PKFMA(zz, sA0, oA0), PKFMA(zz, sA1, oA1)),
                                   PKMAX(PKFMA(zz, sA2, oA2), PKFMA(zz, sA3, oA3)));
                float cvx = fmaxf(tx.x, tx.y);
                floatx2 tn = PKMIN(PKMIN(PKFMA(zz, sC0, oC0), PKFMA(zz, sC1, oC1)),
                                   PKMIN(PKFMA(zz, sC2, oC2), PKFMA(zz, sC3, oC3)));
                float ccv = fminf(tn.x, tn.y);
                float tv = sc.y * cvx + (1.0f - sc.y) * ccv;
                float cpre = accc[mi][ni][r] + sc.z;
                float gpre = accg[mi][ni][r] + sc.w;
                float g = sigm(gpre);
                float cla = gelu_f(cpre);
                obuf[(mb + r) * OSTR + fl] = f2bf(g * tv + (1.0f - g) * cla);
            }
        }
    }
    __syncthreads();   // full 128x128 obuf tile complete
    // cooperative coalesced store: 256B contiguous per row-segment
    #pragma unroll
    for (int e = t; e < 128 * 16; e += 512) {
        int row = e >> 4, c8 = (e & 15) << 3;
        ushort8 v = *(const ushort8*)&obuf[row * OSTR + c8];
        *(ushort8*)&fused[(size_t)(bm * 128 + row) * NF + bf * 128 + c8] = v;
    }
}

// ------------------------------------------------- kernel 5: GEMM2 (fused@Wd + bd)
// r9: double-buffered BK=64, ONE barrier per step (staging overlapped with
// MFMA of the current tile). LDS 64KB (2 bufs x [A 16K | B 16K]).
#define LDS2 64
#define S2B  32768   // bytes per stage buf
__global__ __launch_bounds__(512, 4) void gemm2_kernel(
    const unsigned short* __restrict__ A,  // fused [T][1024]
    const unsigned short* __restrict__ Bt, // WdT [256][1024]
    const float* __restrict__ bd, float* __restrict__ out) {
    __shared__ __align__(16) char smem[65536];
    const int t = threadIdx.x;
    const int b = blockIdx.x;
    const int xcd = b & 7, j = b >> 3;
    const int bn = j & 1;
    const int bm = (j >> 1) * 8 + xcd;
    const int wave = t >> 6, lane = t & 63;
    const int wm = wave & 1, wn = wave >> 1;
    const int lr = lane & 15, quad = lane >> 4;
    const int srow = wave * 8 + (lane >> 3), scol = (lane & 7) << 3;  // 64 rows/issue
    const unsigned short* gA = A  + (size_t)(bm * 128 + srow) * NF + scol;
    const unsigned short* gB = Bt + (size_t)(bn * 128 + srow) * NF + scol;
    const int lofs = wave * 8 * LDS2;   // ushorts

    floatx4 acc[4][2];
    #pragma unroll
    for (int i = 0; i < 4; i++)
        #pragma unroll
        for (int jj = 0; jj < 2; jj++) acc[i][jj] = (floatx4)0.0f;

    {
        unsigned short* b0 = (unsigned short*)smem;           // A [0,8192), B [8192,16384) ushorts
        g2lds16(gA, b0 + lofs);
        g2lds16(gA + (size_t)64 * NF, b0 + 64 * LDS2 + lofs);
        g2lds16(gB, b0 + 8192 + lofs);
        g2lds16(gB + (size_t)64 * NF, b0 + 8192 + 64 * LDS2 + lofs);
    }
    __syncthreads();
    #pragma unroll
    for (int k = 0; k < 16; k++) {
        unsigned short* cur = (unsigned short*)(smem + (size_t)(k & 1) * S2B);
        if (k < 15) {
            unsigned short* nxt = (unsigned short*)(smem + (size_t)((k + 1) & 1) * S2B);
            int k0 = (k + 1) * 64;
            g2lds16(gA + k0, nxt + lofs);
            g2lds16(gA + k0 + (size_t)64 * NF, nxt + 64 * LDS2 + lofs);
            g2lds16(gB + k0, nxt + 8192 + lofs);
            g2lds16(gB + k0 + (size_t)64 * NF, nxt + 8192 + 64 * LDS2 + lofs);
        }
        #pragma unroll
        for (int ks = 0; ks < 2; ks++) {
            bf16x8 af[4], bf_[2];
            #pragma unroll
            for (int mi = 0; mi < 4; mi++)
                af[mi] = *(const bf16x8*)&cur[(wm * 64 + mi * 16 + lr) * LDS2 + ks * 32 + quad * 8];
            #pragma unroll
            for (int ni = 0; ni < 2; ni++)
                bf_[ni] = *(const bf16x8*)&cur[8192 + (wn * 32 + ni * 16 + lr) * LDS2 + ks * 32 + quad * 8];
            #pragma unroll
            for (int mi = 0; mi < 4; mi++)
                #pragma unroll
                for (int ni = 0; ni < 2; ni++)
                    acc[mi][ni] = __builtin_amdgcn_mfma_f32_16x16x32_bf16(af[mi], bf_[ni], acc[mi][ni], 0, 0, 0);
        }
        if (k < 15) __syncthreads();
    }
    #pragma unroll
    for (int mi = 0; mi < 4; mi++)
        #pragma unroll
        for (int ni = 0; ni < 2; ni++) {
            int n = bn * 128 + wn * 32 + ni * 16 + lr;
            float bdv = bd[n];
            #pragma unroll
            for (int r = 0; r < 4; r++) {
                int m = bm * 128 + wm * 64 + mi * 16 + quad * 4 + r;
                out[m * DM + n] = acc[mi][ni][r] + bdv;
            }
        }
}

// ------------------------------------------------------------- launcher
extern "C" void kernel_launch(void* const* d_in, const int* in_sizes, int n_in,
                              void* d_out, int out_size, void* d_ws, size_t ws_size,
                              hipStream_t stream) {
    const float* x     = (const float*)d_in[0];
    const float* Wt    = (const float*)d_in[1];
    const float* bt    = (const float*)d_in[2];
    const float* slx   = (const float*)d_in[3];
    const float* ofx   = (const float*)d_in[4];
    const float* slc   = (const float*)d_in[5];
    const float* ofc   = (const float*)d_in[6];
    const float* alpha = (const float*)d_in[7];
    const float* Wc    = (const float*)d_in[8];
    const float* bc    = (const float*)d_in[9];
    const float* Wg    = (const float*)d_in[10];
    const float* bg    = (const float*)d_in[11];
    const float* Wd    = (const float*)d_in[12];
    const float* bd    = (const float*)d_in[13];
    float* out = (float*)d_out;
    char* ws = (char*)d_ws;

    unsigned int* slot = (unsigned int*)(ws + O_SLOT);
    float* s           = (float*)(ws + O_S);
    unsigned short* Wct = (unsigned short*)(ws + O_WCT);
    unsigned short* Wgt = (unsigned short*)(ws + O_WGT);
    unsigned short* WdT = (unsigned short*)(ws + O_WDT);
    float* WtT          = (float*)(ws + O_WTT);
    unsigned short* xbf = (unsigned short*)(ws + O_XBF);
    int* counts         = (int*)(ws + O_CNT);
    int* cidx           = (int*)(ws + O_CIDX);
    float* cval         = (float*)(ws + O_CVAL);
    unsigned short* fused = (unsigned short*)(ws + O_FUSD);

    hipMemsetAsync(slot, 0, 4, stream);   // init for pack's fused atomicMax
    pack_kernel<<<1024, 256, 0, stream>>>(Wt, alpha, Wc, Wg, Wd, Wct, Wgt, WdT, WtT, s, slot);
    cand_kernel<<<TTOK / 4, 256, 0, stream>>>(x, slot, xbf, counts, cidx, cval);
    gemm1_kernel<<<2048, 512, 0, stream>>>(
        xbf, Wct, Wgt, bc, bg, counts, cidx, cval, x, WtT, bt,
        slx, ofx, slc, ofc, s, fused);
    gemm2_kernel<<<512, 512, 0, stream>>>(fused, WdT, bd, out);
}

// Round 5
// 295.894 us; speedup vs baseline: 1.1975x; 1.1975x over previous
//
#include <hip/hip_runtime.h>

// ---------------------------------------------------------------- constants
#define TTOK 32768
#define DM   256
#define NF   1024
#define KMAX 32

typedef __attribute__((ext_vector_type(8))) unsigned short ushort8;
typedef __attribute__((ext_vector_type(8))) __bf16 bf16x8;
typedef __attribute__((ext_vector_type(4))) float floatx4;
typedef __attribute__((ext_vector_type(2))) float floatx2;

// packed f32 math (lowers to v_pk_fma_f32 / v_pk_max_f32 / v_pk_min_f32)
#define PKFMA(a,b,c) __builtin_elementwise_fma(a,b,c)
#define PKMAX(a,b)   __builtin_elementwise_max(a,b)
#define PKMIN(a,b)   __builtin_elementwise_min(a,b)

// workspace offsets (all 256B aligned)
constexpr size_t O_SLOT = 0;                                   // 1 uint (max|Wt|)
constexpr size_t O_S    = 256;                                 // 1024 f32 sigmoid(alpha)
constexpr size_t O_WCT  = O_S    + 4096;                       // Wc^T  [1024][256] bf16
constexpr size_t O_WGT  = O_WCT  + (size_t)NF*DM*2;            // Wg^T  [1024][256] bf16
constexpr size_t O_WDT  = O_WGT  + (size_t)NF*DM*2;            // Wd^T  [256][1024] bf16
constexpr size_t O_WTT  = O_WDT  + (size_t)DM*NF*2;            // Wt^T  [256][1024] f32
constexpr size_t O_XBF  = O_WTT  + (size_t)DM*NF*4;            // x bf16 [T][256]
constexpr size_t O_CNT  = O_XBF  + (size_t)TTOK*DM*2;          // counts [T]
constexpr size_t O_CIDX = O_CNT  + (size_t)TTOK*4;             // cand d (raw) [T][KMAX]
constexpr size_t O_CVAL = O_CIDX + (size_t)TTOK*KMAX*4;        // cand val [T][KMAX]
constexpr size_t O_FUSD = O_CVAL + (size_t)TTOK*KMAX*4;        // fused bf16 [T][1024]

__device__ __forceinline__ float bf2f(unsigned short u) {
    union { unsigned int i; float f; } c; c.i = ((unsigned int)u) << 16; return c.f;
}
__device__ __forceinline__ unsigned short f2bf(float v) {
    union { float f; unsigned int i; } c; c.f = v;
    unsigned int b = c.i;
    return (unsigned short)((b + 0x7FFFu + ((b >> 16) & 1u)) >> 16);
}
__device__ __forceinline__ float sigm(float z) { return 1.0f / (1.0f + __expf(-z)); }
// tanh-gelu: max |diff| vs exact erf-gelu ~3e-3, far under 0.266 tolerance
__device__ __forceinline__ float gelu_f(float x) {
    return x * sigm(1.59576912f * (x + 0.044715f * x * x * x));
}
// async global->LDS, 16B per lane; lds dest = wave-uniform base + lane*16 [m97/m104]
__device__ __forceinline__ void g2lds16(const unsigned short* g, unsigned short* l) {
    __builtin_amdgcn_global_load_lds((const __attribute__((address_space(1))) unsigned int*)g,
                                     (__attribute__((address_space(3))) unsigned int*)l, 16, 0, 0);
}

// ------------------------------------------------- kernel 1: pack weights (r0 verbatim)
__global__ void pack_kernel(const float* __restrict__ Wt, const float* __restrict__ alpha,
                            const float* __restrict__ Wc, const float* __restrict__ Wg,
                            const float* __restrict__ Wd,
                            unsigned short* __restrict__ Wct, unsigned short* __restrict__ Wgt,
                            unsigned short* __restrict__ WdT, float* __restrict__ WtT,
                            float* __restrict__ s, unsigned int* __restrict__ slot) {
    int e = blockIdx.x * 256 + threadIdx.x;
    if (e == 0) *slot = 0u;
    { int f = e >> 8, k = e & 255;           // Wc/Wg are [256][1024]
      Wct[e] = f2bf(Wc[k * NF + f]);
      Wgt[e] = f2bf(Wg[k * NF + f]); }
    { int n = e >> 10, k = e & 1023;         // Wd is [1024][256]
      WdT[e] = f2bf(Wd[k * DM + n]); }
    { int d = e >> 10, f = e & 1023;         // Wt is [1024][256]
      WtT[e] = Wt[f * DM + d]; }
    if (e < NF) s[e] = sigm(alpha[e]);
}

// ------------------------------------------------- kernel 2: max|Wt| reduce (r0 verbatim)
__global__ void minmax_kernel(const float* __restrict__ Wt, unsigned int* __restrict__ slot) {
    int g = blockIdx.x * 256 + threadIdx.x;
    float lm = 0.0f;
    for (int i = g; i < NF * DM; i += 128 * 256) lm = fmaxf(lm, fabsf(Wt[i]));
    #pragma unroll
    for (int o = 32; o > 0; o >>= 1) lm = fmaxf(lm, __shfl_xor(lm, o));
    if ((threadIdx.x & 63) == 0) atomicMax(slot, __float_as_uint(lm)); // |w|>=0: uint order ok
}

// ------------------------------------------------- kernel 3: candidates + x->bf16 (r0 verbatim)
__global__ void cand_kernel(const float* __restrict__ x, const unsigned int* __restrict__ slot,
                            unsigned short* __restrict__ xbf, int* __restrict__ counts,
                            int* __restrict__ cidx, float* __restrict__ cval) {
    int i = blockIdx.x, t = threadIdx.x;
    float v = x[i * DM + t];
    xbf[i * DM + t] = f2bf(v);
    float m = v;
    #pragma unroll
    for (int o = 32; o > 0; o >>= 1) m = fmaxf(m, __shfl_xor(m, o));
    __shared__ float wm[4];
    __shared__ int cnt;
    __shared__ int sidx[KMAX];
    __shared__ float sval[KMAX];
    if ((t & 63) == 0) wm[t >> 6] = m;
    if (t == 0) cnt = 0;
    __syncthreads();
    float xmax = fmaxf(fmaxf(wm[0], wm[1]), fmaxf(wm[2], wm[3]));
    float delta = 2.0f * __uint_as_float(*slot);   // >= Wmax - Wmin : exact exclusion bound
    float thr = xmax - delta;
    if (v >= thr) {
        int p = atomicAdd(&cnt, 1);
        if (p < KMAX) { sidx[p] = t; sval[p] = v; }   // raw d index
    }
    __syncthreads();
    int c = cnt;
    if (t == 0) counts[i] = c;
    if (t < (c < KMAX ? c : KMAX)) {
        cidx[i * KMAX + t] = sidx[t];
        cval[i * KMAX + t] = sval[t];
    }
}

// ------------------------------------------------- kernel 4: fused GEMM1
// (x@Wc, x@Wg) MFMA + tropical max-plus + convex/concave + gate blend.
// 128x128 tile, BK=32, 512 thr (8 waves 2Mx4F, wave 64x32 dual-output).
// r5 = r0 structure VERBATIM (2-barrier K-loop, post-loop par/sOV staging,
// KMAX=32 meta, obuf at 41984) + the ONE verified gemm1 win transplanted:
// r3's packed-f32 epilogue (floatx2 z-gather + pk_fma/pk_max/pk_min PWL,
// exact r3 text: float4 loads then pair-build; r3 blend forms).
// Ledger:
//  r7(128x64+reg-diet): spills+L2 thrash. REVERTED.
//  r8(DB 1-barrier loop): gemm1 190.6 vs r0 187 -- no win. DROPPED.
//  r8(pre-loop prestage): spills. DROPPED.
//  r9(packed epilogue): gemm1 178.5 vs 190.6 -- THE win. KEPT (r3 text).
//  r10(floatx2-direct par reads + fma blends): correctness FAIL (absmax 0.89,
//    garbage-scale recorded absmax) despite static equivalence. REVERTED to
//    r3-verified text; do not re-derive, transplant only.
#define LDSS 32   // ushorts per LDS row, no pad (wave-uniform-base DMA, m104)
#define KPAD 33
#define OSTR 136  // obuf row stride in ushorts (272B, 16q+4r+col bank spread)
__global__ __launch_bounds__(512, 4) void gemm1_kernel(
    const unsigned short* __restrict__ A,   // xbf [T][256]
    const unsigned short* __restrict__ Bct, // [1024][256]
    const unsigned short* __restrict__ Bgt, // [1024][256]
    const float* __restrict__ bc, const float* __restrict__ bg,
    const int* __restrict__ counts, const int* __restrict__ cidx,
    const float* __restrict__ cval, const float* __restrict__ x,
    const float* __restrict__ WtT, const float* __restrict__ bt,
    const float* __restrict__ slx, const float* __restrict__ ofx,
    const float* __restrict__ slc, const float* __restrict__ ofc,
    const float* __restrict__ s, unsigned short* __restrict__ fused) {
    __shared__ __align__(16) char smem[76800];
    unsigned short* As  = (unsigned short*)smem;            // [0, 8K)     K-loop
    unsigned short* Bcs = As + 4096;                        // [8K, 16K)   K-loop
    unsigned short* Bgs = As + 8192;                        // [16K, 24K)  K-loop
    float* par = (float*)smem;                              // [0, 18K)    epilogue (overlay)
    int* sOV  = (int*)(smem + 24576);                       // [24K, 40.5K)
    int* sCnt = (int*)(smem + 41472);                       // 512B
    unsigned short* obuf = (unsigned short*)(smem + 41984); // 34816B
    const int t = threadIdx.x;
    // XCD-aware swizzle (speed heuristic only; correctness order-free)
    const int b = blockIdx.x;
    const int xcd = b & 7, j = b >> 3;
    const int bf = j & 7;
    const int bm = (j >> 3) * 8 + xcd;
    const int wave = t >> 6, lane = t & 63;
    const int wm = wave & 1, wn = wave >> 1;
    const int lr = lane & 15, quad = lane >> 4;
    const int srow = wave * 16 + (lane >> 2), scol = (lane & 3) << 3;
    const unsigned short* gA = A   + (size_t)(bm * 128 + srow) * DM + scol;
    const unsigned short* gC = Bct + (size_t)(bf * 128 + srow) * DM + scol;
    const unsigned short* gG = Bgt + (size_t)(bf * 128 + srow) * DM + scol;
    unsigned short* lA = &As[wave * 16 * LDSS];
    unsigned short* lC = &Bcs[wave * 16 * LDSS];
    unsigned short* lG = &Bgs[wave * 16 * LDSS];

    if (t < 128) sCnt[t] = counts[bm * 128 + t];

    floatx4 accc[4][2], accg[4][2];
    #pragma unroll
    for (int i = 0; i < 4; i++)
        #pragma unroll
        for (int jj = 0; jj < 2; jj++) { accc[i][jj] = (floatx4)0.0f; accg[i][jj] = (floatx4)0.0f; }

    for (int k0 = 0; k0 < DM; k0 += 32) {
        __syncthreads();            // covers sCnt stage (1st iter) + prior ds_reads
        g2lds16(gA + k0, lA);
        g2lds16(gC + k0, lC);
        g2lds16(gG + k0, lG);
        __syncthreads();
        bf16x8 af[4], bcf[2], bgf[2];
        #pragma unroll
        for (int mi = 0; mi < 4; mi++)
            af[mi] = *(const bf16x8*)&As[(wm * 64 + mi * 16 + lr) * LDSS + quad * 8];
        #pragma unroll
        for (int ni = 0; ni < 2; ni++) {
            bcf[ni] = *(const bf16x8*)&Bcs[(wn * 32 + ni * 16 + lr) * LDSS + quad * 8];
            bgf[ni] = *(const bf16x8*)&Bgs[(wn * 32 + ni * 16 + lr) * LDSS + quad * 8];
        }
        #pragma unroll
        for (int mi = 0; mi < 4; mi++)
            #pragma unroll
            for (int ni = 0; ni < 2; ni++) {
                accc[mi][ni] = __builtin_amdgcn_mfma_f32_16x16x32_bf16(af[mi], bcf[ni], accc[mi][ni], 0, 0, 0);
                accg[mi][ni] = __builtin_amdgcn_mfma_f32_16x16x32_bf16(af[mi], bgf[ni], accg[mi][ni], 0, 0, 0);
            }
    }
    __syncthreads();   // staging bufs dead; overlay par

    // ---- stage epilogue params into LDS: par[fl*36 + {0..7 slx, 8..15 ofx,
    //      16..23 slc, 24..31 ofc, 32 bt, 33 s, 34 bc, 35 bg}]
    for (int e = t; e < 1024; e += 512) {
        int ff = e >> 3, w = e & 7;
        int gf = (bf * 128 + ff) * 8 + w;
        par[ff * 36 + w]      = slx[gf];
        par[ff * 36 + 8 + w]  = ofx[gf];
        par[ff * 36 + 16 + w] = slc[gf];
        par[ff * 36 + 24 + w] = ofc[gf];
    }
    if (t < 128) {
        int gf = bf * 128 + t;
        par[t * 36 + 32] = bt[gf];
        par[t * 36 + 33] = s[gf];
        par[t * 36 + 34] = bc[gf];
        par[t * 36 + 35] = bg[gf];
    }
    // ---- stage packed candidate meta (pre-padded: d=0, val=-1e30 -> branchless)
    const int PADV = (int)(((unsigned int)f2bf(-1e30f)) << 16);
    for (int e = t; e < 128 * KMAX; e += 512) {
        int m = e >> 5, k = e & 31;
        int c = sCnt[m];
        int pk = PADV;
        if (k < (c < KMAX ? c : KMAX)) {
            int d  = cidx[(size_t)(bm * 128 + m) * KMAX + k];
            float v = cval[(size_t)(bm * 128 + m) * KMAX + k];
            pk = (int)(((unsigned int)f2bf(v)) << 16) | d;
        }
        sOV[m * KPAD + k] = pk;
    }
    __syncthreads();

    // ---- fused epilogue: tropical z + convex/concave + gate blend ----
    // C/D layout col=lane&15, row=quad*4+r  [verified m89/m91]
    const int f0 = bf * 128 + wn * 32 + lr;    // ni=0 global f; ni=1 is +16
    #pragma unroll
    for (int mi = 0; mi < 4; mi++) {
        const int mb = wm * 64 + mi * 16 + quad * 4;   // local m of r=0
        int c0 = sCnt[mb], c1 = sCnt[mb + 1], c2 = sCnt[mb + 2], c3 = sCnt[mb + 3];
        int k0c = c0 < KMAX ? c0 : KMAX, k1c = c1 < KMAX ? c1 : KMAX;
        int k2c = c2 < KMAX ? c2 : KMAX, k3c = c3 < KMAX ? c3 : KMAX;
        int km = max(max(k0c, k1c), max(k2c, k3c));
        // z packed across the (f0, f0+16) column pair: .x = ni0, .y = ni1  [r3-verified]
        floatx2 zp0 = { -1e30f, -1e30f }, zp1 = zp0, zp2 = zp0, zp3 = zp0;
        for (int k = 0; k < km; k++) {
            int p0 = sOV[(mb + 0) * KPAD + k];
            int p1 = sOV[(mb + 1) * KPAD + k];
            int p2 = sOV[(mb + 2) * KPAD + k];
            int p3 = sOV[(mb + 3) * KPAD + k];
            const float* r0 = WtT + ((p0 & 0xFFFF) << 10) + f0;
            const float* r1 = WtT + ((p1 & 0xFFFF) << 10) + f0;
            const float* r2 = WtT + ((p2 & 0xFFFF) << 10) + f0;
            const float* r3 = WtT + ((p3 & 0xFFFF) << 10) + f0;
            floatx2 w0 = { r0[0], r0[16] };
            floatx2 w1 = { r1[0], r1[16] };
            floatx2 w2 = { r2[0], r2[16] };
            floatx2 w3 = { r3[0], r3[16] };
            float s0 = __int_as_float(p0 & 0xFFFF0000);
            float s1 = __int_as_float(p1 & 0xFFFF0000);
            float s2 = __int_as_float(p2 & 0xFFFF0000);
            float s3 = __int_as_float(p3 & 0xFFFF0000);
            floatx2 v0 = { s0, s0 }, v1 = { s1, s1 }, v2 = { s2, s2 }, v3 = { s3, s3 };
            zp0 = PKMAX(zp0, v0 + w0);
            zp1 = PKMAX(zp1, v1 + w1);
            zp2 = PKMAX(zp2, v2 + w2);
            zp3 = PKMAX(zp3, v3 + w3);
        }
        // exact fallback (count > KMAX, ~never): full 256-d scan
        if (c0 > KMAX || c1 > KMAX || c2 > KMAX || c3 > KMAX) {
            float za[4] = { zp0.x, zp1.x, zp2.x, zp3.x };
            float zb[4] = { zp0.y, zp1.y, zp2.y, zp3.y };
            int cc[4] = { c0, c1, c2, c3 };
            #pragma unroll 1
            for (int r = 0; r < 4; r++) if (cc[r] > KMAX) {
                const float* xr = x + (size_t)(bm * 128 + mb + r) * DM;
                float ma = -1e30f, mbv = -1e30f;
                for (int d = 0; d < DM; d++) {
                    float xv = xr[d];
                    ma  = fmaxf(ma,  xv + WtT[d * NF + f0]);
                    mbv = fmaxf(mbv, xv + WtT[d * NF + f0 + 16]);
                }
                za[r] = ma; zb[r] = mbv;
            }
            zp0.x = za[0]; zp1.x = za[1]; zp2.x = za[2]; zp3.x = za[3];
            zp0.y = zb[0]; zp1.y = zb[1]; zp2.y = zb[2]; zp3.y = zb[3];
        }
        #pragma unroll
        for (int ni = 0; ni < 2; ni++) {
            const int fl = wn * 32 + ni * 16 + lr;
            const float* pp = par + fl * 36;
            float4 a0 = *(const float4*)(pp),      a1 = *(const float4*)(pp + 4);
            float4 b0 = *(const float4*)(pp + 8),  b1 = *(const float4*)(pp + 12);
            float4 cc0 = *(const float4*)(pp + 16), cc1 = *(const float4*)(pp + 20);
            float4 d0 = *(const float4*)(pp + 24), d1 = *(const float4*)(pp + 28);
            float4 sc = *(const float4*)(pp + 32);  // bt, s, bc, bg
            // segment-pair packing for the PWL hulls (v_pk_fma/pk_max/pk_min) [r3-verified]
            floatx2 sA0 = { a0.x, a0.y }, sA1 = { a0.z, a0.w };
            floatx2 sA2 = { a1.x, a1.y }, sA3 = { a1.z, a1.w };
            floatx2 oA0 = { b0.x, b0.y }, oA1 = { b0.z, b0.w };
            floatx2 oA2 = { b1.x, b1.y }, oA3 = { b1.z, b1.w };
            floatx2 sC0 = { cc0.x, cc0.y }, sC1 = { cc0.z, cc0.w };
            floatx2 sC2 = { cc1.x, cc1.y }, sC3 = { cc1.z, cc1.w };
            floatx2 oC0 = { d0.x, d0.y }, oC1 = { d0.z, d0.w };
            floatx2 oC2 = { d1.x, d1.y }, oC3 = { d1.z, d1.w };
            float zr[4];
            if (ni == 0) { zr[0] = zp0.x; zr[1] = zp1.x; zr[2] = zp2.x; zr[3] = zp3.x; }
            else         { zr[0] = zp0.y; zr[1] = zp1.y; zr[2] = zp2.y; zr[3] = zp3.y; }
            #pragma unroll
            for (int r = 0; r < 4; r++) {
                float zv = zr[r] + sc.x;
                floatx2 zz = { zv, zv };
                floatx2 tx = PKMAX(PKMAX(PKFMA(zz, sA0, oA0), PKFMA(zz, sA1, oA1)),
                                   PKMAX(PKFMA(zz, sA2, oA2), PKFMA(zz, sA3, oA3)));
                float cvx = fmaxf(tx.x, tx.y);
                floatx2 tn = PKMIN(PKMIN(PKFMA(zz, sC0, oC0), PKFMA(zz, sC1, oC1)),
                                   PKMIN(PKFMA(zz, sC2, oC2), PKFMA(zz, sC3, oC3)));
                float ccv = fminf(tn.x, tn.y);
                float tv = sc.y * cvx + (1.0f - sc.y) * ccv;
                float cpre = accc[mi][ni][r] + sc.z;
                float gpre = accg[mi][ni][r] + sc.w;
                float g = sigm(gpre);
                float cla = gelu_f(cpre);
                obuf[(mb + r) * OSTR + fl] = f2bf(g * tv + (1.0f - g) * cla);
            }
        }
    }
    __syncthreads();   // full 128x128 obuf tile complete
    // cooperative coalesced store: 256B contiguous per row-segment
    #pragma unroll
    for (int e = t; e < 128 * 16; e += 512) {
        int row = e >> 4, c8 = (e & 15) << 3;
        ushort8 v = *(const ushort8*)&obuf[row * OSTR + c8];
        *(ushort8*)&fused[(size_t)(bm * 128 + row) * NF + bf * 128 + c8] = v;
    }
}

// ------------------------------------------------- kernel 5: GEMM2 (fused@Wd + bd) (r0 verbatim)
#define LDS2 64
__global__ __launch_bounds__(512, 4) void gemm2_kernel(
    const unsigned short* __restrict__ A,  // fused [T][1024]
    const unsigned short* __restrict__ Bt, // WdT [256][1024]
    const float* __restrict__ bd, float* __restrict__ out) {
    __shared__ __align__(16) unsigned short As[128 * LDS2];
    __shared__ __align__(16) unsigned short Bs[128 * LDS2];
    const int t = threadIdx.x;
    const int b = blockIdx.x;
    const int xcd = b & 7, j = b >> 3;
    const int bn = j & 1;
    const int bm = (j >> 1) * 8 + xcd;
    const int wave = t >> 6, lane = t & 63;
    const int wm = wave & 1, wn = wave >> 1;
    const int lr = lane & 15, quad = lane >> 4;
    const int srow = wave * 8 + (lane >> 3), scol = (lane & 7) << 3;  // 64 rows/issue
    const unsigned short* gA = A  + (size_t)(bm * 128 + srow) * NF + scol;
    const unsigned short* gB = Bt + (size_t)(bn * 128 + srow) * NF + scol;
    unsigned short* lA = &As[wave * 8 * LDS2];
    unsigned short* lB = &Bs[wave * 8 * LDS2];

    floatx4 acc[4][2];
    #pragma unroll
    for (int i = 0; i < 4; i++)
        #pragma unroll
        for (int jj = 0; jj < 2; jj++) acc[i][jj] = (floatx4)0.0f;

    for (int k0 = 0; k0 < NF; k0 += 64) {
        __syncthreads();
        g2lds16(gA + k0, lA);
        g2lds16(gA + k0 + (size_t)64 * NF, lA + 64 * LDS2);
        g2lds16(gB + k0, lB);
        g2lds16(gB + k0 + (size_t)64 * NF, lB + 64 * LDS2);
        __syncthreads();
        #pragma unroll
        for (int ks = 0; ks < 2; ks++) {
            bf16x8 af[4], bf_[2];
            #pragma unroll
            for (int mi = 0; mi < 4; mi++)
                af[mi] = *(const bf16x8*)&As[(wm * 64 + mi * 16 + lr) * LDS2 + ks * 32 + quad * 8];
            #pragma unroll
            for (int ni = 0; ni < 2; ni++)
                bf_[ni] = *(const bf16x8*)&Bs[(wn * 32 + ni * 16 + lr) * LDS2 + ks * 32 + quad * 8];
            #pragma unroll
            for (int mi = 0; mi < 4; mi++)
                #pragma unroll
                for (int ni = 0; ni < 2; ni++)
                    acc[mi][ni] = __builtin_amdgcn_mfma_f32_16x16x32_bf16(af[mi], bf_[ni], acc[mi][ni], 0, 0, 0);
        }
    }
    #pragma unroll
    for (int mi = 0; mi < 4; mi++)
        #pragma unroll
        for (int ni = 0; ni < 2; ni++) {
            int n = bn * 128 + wn * 32 + ni * 16 + lr;
            float bdv = bd[n];
            #pragma unroll
            for (int r = 0; r < 4; r++) {
                int m = bm * 128 + wm * 64 + mi * 16 + quad * 4 + r;
                out[m * DM + n] = acc[mi][ni][r] + bdv;
            }
        }
}

// ------------------------------------------------------------- launcher (r0 verbatim)
extern "C" void kernel_launch(void* const* d_in, const int* in_sizes, int n_in,
                              void* d_out, int out_size, void* d_ws, size_t ws_size,
                              hipStream_t stream) {
    const float* x     = (const float*)d_in[0];
    const float* Wt    = (const float*)d_in[1];
    const float* bt    = (const float*)d_in[2];
    const float* slx   = (const float*)d_in[3];
    const float* ofx   = (const float*)d_in[4];
    const float* slc   = (const float*)d_in[5];
    const float* ofc   = (const float*)d_in[6];
    const float* alpha = (const float*)d_in[7];
    const float* Wc    = (const float*)d_in[8];
    const float* bc    = (const float*)d_in[9];
    const float* Wg    = (const float*)d_in[10];
    const float* bg    = (const float*)d_in[11];
    const float* Wd    = (const float*)d_in[12];
    const float* bd    = (const float*)d_in[13];
    float* out = (float*)d_out;
    char* ws = (char*)d_ws;

    unsigned int* slot = (unsigned int*)(ws + O_SLOT);
    float* s           = (float*)(ws + O_S);
    unsigned short* Wct = (unsigned short*)(ws + O_WCT);
    unsigned short* Wgt = (unsigned short*)(ws + O_WGT);
    unsigned short* WdT = (unsigned short*)(ws + O_WDT);
    float* WtT          = (float*)(ws + O_WTT);
    unsigned short* xbf = (unsigned short*)(ws + O_XBF);
    int* counts         = (int*)(ws + O_CNT);
    int* cidx           = (int*)(ws + O_CIDX);
    float* cval         = (float*)(ws + O_CVAL);
    unsigned short* fused = (unsigned short*)(ws + O_FUSD);

    pack_kernel<<<1024, 256, 0, stream>>>(Wt, alpha, Wc, Wg, Wd, Wct, Wgt, WdT, WtT, s, slot);
    minmax_kernel<<<128, 256, 0, stream>>>(Wt, slot);
    cand_kernel<<<TTOK, 256, 0, stream>>>(x, slot, xbf, counts, cidx, cval);
    gemm1_kernel<<<2048, 512, 0, stream>>>(
        xbf, Wct, Wgt, bc, bg, counts, cidx, cval, x, WtT, bt,
        slx, ofx, slc, ofc, s, fused);
    gemm2_kernel<<<512, 512, 0, stream>>>(fused, WdT, bd, out);
}